// Round 10
// baseline (238.529 us; speedup 1.0000x reference)
//
#include <hip/hip_runtime.h>

#define NUM_EMB 1024
#define EMB_DIM 256
#define NPIX    32768      // 32 * 32 * 32
#define HW      1024       // 32*32 spatial per batch
#define ZQ_ELEMS 8388608   // 32*256*32*32

// ws layout (bytes):
//   [0..8)                  double loss_accum
//   [8..8+4096)             float  tnorm[1024]
//   [8192..8192+131072)     float  snorm[32768]
//   [139264..+262144)       u64    keys[32768]  (argmin: (d_bits<<32)|idx)
//   [401408..+4)            u32    ticket counter
//   [401424..+1572864)      u16    eG planes in LDS-order [nt][kt][p][q][128][8]
#define WS_TNORM 8
#define WS_SNORM 8192
#define WS_KEYS  139264
#define WS_CNT   401408
#define WS_EG    401424

typedef unsigned long long u64;
typedef unsigned int u32;
typedef unsigned short u16;

typedef __bf16 bf16x8 __attribute__((ext_vector_type(8)));
typedef float f32x16 __attribute__((ext_vector_type(16)));
typedef u16 u16x8 __attribute__((ext_vector_type(8)));

// ---- numpy pairwise_sum replica over 128 squared terms, stride between terms ----
__device__ __forceinline__ float pw128_sq(const float* x, int stride) {
  float r[8];
#pragma unroll
  for (int j = 0; j < 8; ++j) {
    float v = x[(size_t)j * stride];
    r[j] = __fmul_rn(v, v);
  }
  for (int i = 8; i < 128; i += 8) {
#pragma unroll
    for (int j = 0; j < 8; ++j) {
      float v = x[(size_t)(i + j) * stride];
      r[j] = __fadd_rn(r[j], __fmul_rn(v, v));
    }
  }
  float s01 = __fadd_rn(r[0], r[1]);
  float s23 = __fadd_rn(r[2], r[3]);
  float s45 = __fadd_rn(r[4], r[5]);
  float s67 = __fadd_rn(r[6], r[7]);
  return __fadd_rn(__fadd_rn(s01, s23), __fadd_rn(s45, s67));
}

// 3-way bf16 split: x = hf + mf + lf + eps, eps ~ 2^-26 |x|. Sterbenz-exact residuals.
__device__ __forceinline__ void split3(float x, u16& h, u16& m, u16& l) {
  u32 u = __float_as_uint(x);
  u16 hb = (u16)((u + 0x7fffu + ((u >> 16) & 1u)) >> 16);
  float hf = __uint_as_float((u32)hb << 16);
  float r1 = x - hf;                       // exact
  u32 u1 = __float_as_uint(r1);
  u16 mb = (u16)((u1 + 0x7fffu + ((u1 >> 16) & 1u)) >> 16);
  float mf = __uint_as_float((u32)mb << 16);
  float r2 = r1 - mf;                      // exact
  u32 u2 = __float_as_uint(r2);
  u16 lb = (u16)((u2 + 0x7fffu + ((u2 >> 16) & 1u)) >> 16);
  h = hb; m = mb; l = lb;
}

__device__ __forceinline__ u64 shfl_xor_u64(u64 v, int msk) {
  const u32 lo = __shfl_xor((u32)v, msk, 64);
  const u32 hi = __shfl_xor((u32)(v >> 32), msk, 64);
  return ((u64)hi << 32) | lo;
}

// ---- prep: keys=~0, loss=0, cnt=0, snorm (blk 0..127); tnorm + e-split into
//      LDS-order planes eG[nt][kt][p][q][er][8] (blk 128..131) ----
__global__ __launch_bounds__(256) void vq_prep_kernel(
    const float* __restrict__ z, const float* __restrict__ emb,
    float* __restrict__ tnorm, float* __restrict__ snorm,
    u64* __restrict__ keys, double* __restrict__ loss_accum,
    u32* __restrict__ counter, u16* __restrict__ eG) {
  const int gid = blockIdx.x * 256 + threadIdx.x;
  if (gid == 0) *loss_accum = 0.0;
  if (gid == 1) *counter = 0u;
  if (gid < NPIX) {
    keys[gid] = ~0ull;
    const int b = gid >> 10, hw = gid & 1023;
    const float* base = z + (size_t)b * (EMB_DIM * HW) + hw;
    snorm[gid] = __fadd_rn(pw128_sq(base, HW), pw128_sq(base + (size_t)128 * HW, HW));
  } else {
    const int k = gid - NPIX;
    if (k < NUM_EMB) {
      const float* row = emb + (size_t)k * EMB_DIM;
      tnorm[k] = __fadd_rn(pw128_sq(row, 1), pw128_sq(row + 128, 1));
      const int nt = k >> 7, er = k & 127;
      for (int c8 = 0; c8 < 32; ++c8) {
        const int c = c8 * 8, kt = c8 >> 2, qq = c8 & 3;
        u16x8 vh, vm, vl;
#pragma unroll
        for (int j = 0; j < 8; ++j) {
          u16 h_, m_, l_;
          split3(row[c + j], h_, m_, l_);
          vh[j] = h_; vm[j] = m_; vl[j] = l_;
        }
        u16* dst = eG + ((((size_t)(nt * 8 + kt) * 3 + 0) * 4 + qq) * 128 + er) * 8;
        *(u16x8*)(dst)                 = vh;
        *(u16x8*)(dst + 4096)          = vm;   // p stride = 4*128*8 = 4096 u16
        *(u16x8*)(dst + 8192)          = vl;
      }
    }
  }
}

// ---- main: 128 px x 128 codes, 512 threads, double-buffered LDS, ONE raw
// barrier per kt (counted vmcnt pipelining across the barrier — T3-lite).
// 80B LDS rows (measured conflict-free R6/R9). Accumulation order bit-identical
// to validated R9.  XCD swizzle: h -> (h&7)*256 + (h>>3)
__global__ __launch_bounds__(512, 1) void vq_main_kernel(
    const float* __restrict__ z, const u16* __restrict__ eG,
    const float* __restrict__ tnorm, const float* __restrict__ snorm,
    u64* __restrict__ keys) {
  __shared__ __align__(16) u16 zs[2][3][128][40];   // 61440 B
  __shared__ __align__(16) u16 es[2][3][128][40];   // 61440 B
  __shared__ u64 part[128][4];                      // 4096 B

  const int t   = threadIdx.x;
  const int hb  = blockIdx.x;
  const int bid = (hb & 7) * 256 + (hb >> 3);
  const int pt  = bid >> 3;
  const int ntb = bid & 7;
  const int m0  = pt * 128;
  const int n0  = ntb * 128;
  const int b   = m0 >> 10;
  const int hw0 = m0 & 1023;
  const float* zbase = z + (size_t)b * (EMB_DIM * HW) + hw0;

  const int l    = t & 63;
  const int wid  = t >> 6;        // 8 waves: wp = wid>>2 (px half), wq = wid&3
  const int wpx0 = (wid >> 2) * 64;
  const int wcb  = (wid & 3) * 32;
  const int cl   = l & 31;
  const int hi   = l >> 5;

  // staging: thread owns pixel/code row sr and k-octet q (8 k's)
  const int sr = t & 127;
  const int q  = t >> 7;          // 0..3

  float gz[8];
  u16x8 ge[3];

  auto load_z = [&](int kt) {
#pragma unroll
    for (int j = 0; j < 8; ++j)
      gz[j] = zbase[(size_t)(kt * 32 + q * 8 + j) * HW + sr];
  };
  auto load_e = [&](int kt) {
#pragma unroll
    for (int p = 0; p < 3; ++p)
      ge[p] = *(const u16x8*)(eG +
          ((((size_t)(ntb * 8 + kt) * 3 + p) * 4 + q) * 128 + sr) * 8);
  };
  auto stage = [&](int buf) {
    u16x8 vh, vm, vl;
#pragma unroll
    for (int j = 0; j < 8; ++j) {
      u16 h_, m_, l_;
      split3(gz[j], h_, m_, l_);
      vh[j] = h_; vm[j] = m_; vl[j] = l_;
    }
    *(u16x8*)&zs[buf][0][sr][q * 8] = vh;
    *(u16x8*)&zs[buf][1][sr][q * 8] = vm;
    *(u16x8*)&zs[buf][2][sr][q * 8] = vl;
#pragma unroll
    for (int p = 0; p < 3; ++p)
      *(u16x8*)&es[buf][p][sr][q * 8] = ge[p];
  };

  f32x16 acc[2];
#pragma unroll
  for (int i = 0; i < 2; ++i)
#pragma unroll
    for (int r = 0; r < 16; ++r) acc[i][r] = 0.0f;

  // prologue: stage kt=0 into buf0; issue kt=1 loads; raw barrier (no vm drain)
  load_z(0); load_e(0);
  stage(0);
  load_z(1); load_e(1);
  asm volatile("s_waitcnt lgkmcnt(0)" ::: "memory");
  __builtin_amdgcn_s_barrier();

#pragma unroll 2
  for (int kt = 0; kt < 8; ++kt) {
    const int cur = kt & 1;
    // stage kt+1 into other buffer (vmcnt waits are counted: loads issued a
    // full phase ago), then issue kt+2 loads (stay in flight across barrier)
    if (kt < 7) {
      stage(cur ^ 1);
      if (kt < 6) { load_z(kt + 2); load_e(kt + 2); }
    }
    // compute on buf[cur]
#pragma unroll
    for (int ks = 0; ks < 2; ++ks) {
      bf16x8 af[3][2], bf[3];
#pragma unroll
      for (int p = 0; p < 3; ++p) {
#pragma unroll
        for (int mt = 0; mt < 2; ++mt)
          af[p][mt] = *(const bf16x8*)
              &zs[cur][p][wpx0 + mt * 32 + cl][ks * 16 + hi * 8];
        bf[p] = *(const bf16x8*)&es[cur][p][wcb + cl][ks * 16 + hi * 8];
      }
      // 6 split-product planes: hh, hm, mh, mm, hl, lh (order = R9, bit-exact)
#define PROD(PA, PB)                                                          \
      acc[0] = __builtin_amdgcn_mfma_f32_32x32x16_bf16(af[PA][0], bf[PB],     \
                                                       acc[0], 0, 0, 0);      \
      acc[1] = __builtin_amdgcn_mfma_f32_32x32x16_bf16(af[PA][1], bf[PB],     \
                                                       acc[1], 0, 0, 0);
      PROD(0, 0)
      PROD(0, 1)
      PROD(1, 0)
      PROD(1, 1)
      PROD(0, 2)
      PROD(2, 0)
#undef PROD
    }
    if (kt < 7) {
      // drain own DS ops only; raw barrier keeps global prefetch in flight
      asm volatile("s_waitcnt lgkmcnt(0)" ::: "memory");
      __builtin_amdgcn_s_barrier();
    }
  }

  // ---- epilogue: d = fl(fl(s+t) - 2m); argmin via u64 keys ----
  // C layout (validated R6-R9): col = cl (code), row = (reg&3)+8*(reg>>2)+4*hi
  const float tv = tnorm[n0 + wcb + cl];
  u64 bk[2][16];
#pragma unroll
  for (int mt = 0; mt < 2; ++mt)
#pragma unroll
    for (int reg = 0; reg < 16; ++reg) {
      const int row = wpx0 + mt * 32 + (reg & 3) + 8 * (reg >> 2) + 4 * hi;
      const float s = snorm[m0 + row];
      const float d = __fsub_rn(__fadd_rn(s, tv), 2.0f * acc[mt][reg]);
      bk[mt][reg] =
          ((u64)__float_as_uint(d) << 32) | (u32)(n0 + wcb + cl);
    }
  // reduce across the 32 cl-lanes (same rows, different codes)
#pragma unroll
  for (int off = 1; off < 32; off <<= 1) {
#pragma unroll
    for (int mt = 0; mt < 2; ++mt)
#pragma unroll
      for (int reg = 0; reg < 16; ++reg) {
        const u64 o = shfl_xor_u64(bk[mt][reg], off);
        if (o < bk[mt][reg]) bk[mt][reg] = o;
      }
  }

  if (cl == 0) {
#pragma unroll
    for (int mt = 0; mt < 2; ++mt)
#pragma unroll
      for (int reg = 0; reg < 16; ++reg) {
        const int row = wpx0 + mt * 32 + (reg & 3) + 8 * (reg >> 2) + 4 * hi;
        part[row][wid & 3] = bk[mt][reg];
      }
  }
  __syncthreads();
  if (t < 128) {
    u64 best = part[t][0];
#pragma unroll
    for (int x = 1; x < 4; ++x) {
      const u64 o = part[t][x];
      if (o < best) best = o;
    }
    atomicMin(&keys[m0 + t], best);
  }
}

// ---- outputs: z_q gather + straight-through + loss + idx; last block finalizes ----
__global__ __launch_bounds__(256) void vq_outputs_kernel(
    const float* __restrict__ z, const float* __restrict__ emb,
    const u64* __restrict__ keys, float* __restrict__ out,
    float* __restrict__ out_idx_f, double* __restrict__ loss_accum,
    u32* __restrict__ counter, float* __restrict__ out_loss) {
  const int t  = threadIdx.x;
  const int n0 = blockIdx.x * 64;
  const int m  = t & 63;
  const int c0 = t >> 6;
  const int b  = n0 >> 10;
  const int hw = n0 & 1023;
  const float* zb = z   + (size_t)b * (EMB_DIM * HW) + hw + m;
  float*       ob = out + (size_t)b * (EMB_DIM * HW) + hw + m;
  const int idx = (int)(u32)(keys[n0 + m] & 0xffffffffu);
  const float* er = emb + (size_t)idx * EMB_DIM;
  if (c0 == 0) out_idx_f[n0 + m] = (float)idx;

  double lsum = 0.0;
  for (int c = c0; c < EMB_DIM; c += 4) {
    const float e  = er[c];
    const float zv = zb[(size_t)c * HW];
    const float diff = e - zv;       // fl(z_q - z)
    const float zq   = zv + diff;    // straight-through: fl(z + fl(z_q - z))
    ob[(size_t)c * HW] = zq;
    lsum += (double)diff * (double)diff;
  }

  __shared__ double red[256];
  red[t] = lsum;
  __syncthreads();
  for (int s2 = 128; s2 > 0; s2 >>= 1) {
    if (t < s2) red[t] += red[t + s2];
    __syncthreads();
  }
  if (t == 0) {
    atomicAdd(loss_accum, red[0]);
    __threadfence();
    const u32 tick = atomicAdd(counter, 1u);
    if (tick == (u32)(NPIX / 64 - 1)) {
      const double total = atomicAdd(loss_accum, 0.0);  // device-scope read
      const float L = (float)(total / (double)ZQ_ELEMS);
      out_loss[0] = __fadd_rn(L, __fmul_rn(0.25f, L));
    }
  }
}

extern "C" void kernel_launch(void* const* d_in, const int* in_sizes, int n_in,
                              void* d_out, int out_size, void* d_ws, size_t ws_size,
                              hipStream_t stream) {
  const float* z   = (const float*)d_in[0];   // (32, 256, 32, 32) f32
  const float* emb = (const float*)d_in[1];   // (1024, 256) f32

  float* out       = (float*)d_out;           // z_q_out (B,C,H,W)
  float* out_loss  = out + ZQ_ELEMS;          // vq_loss scalar
  float* out_idx_f = out + ZQ_ELEMS + 1;      // encoding_indices as f32

  double* loss_accum = (double*)d_ws;
  float*  tnorm = (float*)((char*)d_ws + WS_TNORM);
  float*  snorm = (float*)((char*)d_ws + WS_SNORM);
  u64*    keys  = (u64*)((char*)d_ws + WS_KEYS);
  u32*    counter = (u32*)((char*)d_ws + WS_CNT);
  u16*    eG    = (u16*)((char*)d_ws + WS_EG);

  vq_prep_kernel<<<132, 256, 0, stream>>>(z, emb, tnorm, snorm, keys, loss_accum,
                                          counter, eG);
  vq_main_kernel<<<2048, 512, 0, stream>>>(z, eG, tnorm, snorm, keys);
  vq_outputs_kernel<<<NPIX / 64, 256, 0, stream>>>(z, emb, keys, out, out_idx_f,
                                                   loss_accum, counter, out_loss);
}

// Round 11
// 204.457 us; speedup vs baseline: 1.1666x; 1.1666x over previous
//
#include <hip/hip_runtime.h>

#define NUM_EMB 1024
#define EMB_DIM 256
#define NPIX    32768      // 32 * 32 * 32
#define HW      1024       // 32*32 spatial per batch
#define ZQ_ELEMS 8388608   // 32*256*32*32

// ws layout (bytes):
//   [0..8)                  double loss_accum
//   [8..8+4096)             float  tnorm[1024]
//   [8192..+131072)         float  snorm[32768]
//   [139264..+262144)       u64    keys[32768]  (argmin: (d_bits<<32)|idx)
//   [401408..+4)            u32    ticket counter
//   [403456..+1572864)      u16    EB: e B-fragment planes [3][32][8][2][2][32][8]
#define WS_TNORM 8
#define WS_SNORM 8192
#define WS_KEYS  139264
#define WS_CNT   401408
#define WS_EB    403456

typedef unsigned long long u64;
typedef unsigned int u32;
typedef unsigned short u16;

typedef __bf16 bf16x8 __attribute__((ext_vector_type(8)));
typedef float f32x16 __attribute__((ext_vector_type(16)));
typedef u16 u16x8 __attribute__((ext_vector_type(8)));

// B-fragment-ordered e-planes (validated R8): lane (hi,cl) reads 16B contiguous;
// 64 lanes = 1KB coalesced chunk per (p, g=code>>5, kt, ks).
__device__ __forceinline__ size_t eb_idx(int p, int g, int kt, int ks, int hi,
                                         int cl) {
  return ((((((size_t)p * 32 + g) * 8 + kt) * 2 + ks) * 2 + hi) * 32 + cl) * 8;
}

// ---- numpy pairwise_sum replica over 128 squared terms, stride between terms ----
__device__ __forceinline__ float pw128_sq(const float* x, int stride) {
  float r[8];
#pragma unroll
  for (int j = 0; j < 8; ++j) {
    float v = x[(size_t)j * stride];
    r[j] = __fmul_rn(v, v);
  }
  for (int i = 8; i < 128; i += 8) {
#pragma unroll
    for (int j = 0; j < 8; ++j) {
      float v = x[(size_t)(i + j) * stride];
      r[j] = __fadd_rn(r[j], __fmul_rn(v, v));
    }
  }
  float s01 = __fadd_rn(r[0], r[1]);
  float s23 = __fadd_rn(r[2], r[3]);
  float s45 = __fadd_rn(r[4], r[5]);
  float s67 = __fadd_rn(r[6], r[7]);
  return __fadd_rn(__fadd_rn(s01, s23), __fadd_rn(s45, s67));
}

// 3-way bf16 split: x = hf + mf + lf + eps, eps ~ 2^-26 |x|. Sterbenz-exact residuals.
__device__ __forceinline__ void split3(float x, u16& h, u16& m, u16& l) {
  u32 u = __float_as_uint(x);
  u16 hb = (u16)((u + 0x7fffu + ((u >> 16) & 1u)) >> 16);
  float hf = __uint_as_float((u32)hb << 16);
  float r1 = x - hf;                       // exact
  u32 u1 = __float_as_uint(r1);
  u16 mb = (u16)((u1 + 0x7fffu + ((u1 >> 16) & 1u)) >> 16);
  float mf = __uint_as_float((u32)mb << 16);
  float r2 = r1 - mf;                      // exact
  u32 u2 = __float_as_uint(r2);
  u16 lb = (u16)((u2 + 0x7fffu + ((u2 >> 16) & 1u)) >> 16);
  h = hb; m = mb; l = lb;
}

__device__ __forceinline__ u64 shfl_xor_u64(u64 v, int msk) {
  const u32 lo = __shfl_xor((u32)v, msk, 64);
  const u32 hi = __shfl_xor((u32)(v >> 32), msk, 64);
  return ((u64)hi << 32) | lo;
}

// ---- prep: keys=~0, loss=0, cnt=0, snorm (blk 0..127);
//      tnorm + e-split into B-frag layout EB (blk 128..131) — validated R8 ----
__global__ __launch_bounds__(256) void vq_prep_kernel(
    const float* __restrict__ z, const float* __restrict__ emb,
    float* __restrict__ tnorm, float* __restrict__ snorm,
    u64* __restrict__ keys, double* __restrict__ loss_accum,
    u32* __restrict__ counter, u16* __restrict__ EB) {
  const int gid = blockIdx.x * 256 + threadIdx.x;
  if (gid == 0) *loss_accum = 0.0;
  if (gid == 1) *counter = 0u;
  if (gid < NPIX) {
    keys[gid] = ~0ull;
    const int b = gid >> 10, hw = gid & 1023;
    const float* base = z + (size_t)b * (EMB_DIM * HW) + hw;
    snorm[gid] = __fadd_rn(pw128_sq(base, HW), pw128_sq(base + (size_t)128 * HW, HW));
  } else {
    const int k = gid - NPIX;
    if (k < NUM_EMB) {
      const float* row = emb + (size_t)k * EMB_DIM;
      tnorm[k] = __fadd_rn(pw128_sq(row, 1), pw128_sq(row + 128, 1));
      const int g = k >> 5, cl = k & 31;
      for (int c = 0; c < EMB_DIM; c += 8) {
        u16x8 vh, vm, vl;
#pragma unroll
        for (int j = 0; j < 8; ++j) {
          u16 h_, m_, l_;
          split3(row[c + j], h_, m_, l_);
          vh[j] = h_; vm[j] = m_; vl[j] = l_;
        }
        const int kt = c >> 5, ks = (c >> 4) & 1, hi = (c >> 3) & 1;
        *(u16x8*)(EB + eb_idx(0, g, kt, ks, hi, cl)) = vh;
        *(u16x8*)(EB + eb_idx(1, g, kt, ks, hi, cl)) = vm;
        *(u16x8*)(EB + eb_idx(2, g, kt, ks, hi, cl)) = vl;
      }
    }
  }
}

// ---- main: 128 px x 128 codes per block, 4 waves, WAVE-PRIVATE everything:
// each wave owns a 64px x 64code C-tile; A staged in its private LDS region
// (in-order DS pipe -> no barriers); B direct from EB frag layout (L2-hot,
// coalesced). ZERO __syncthreads in the k-loop. 32x32x16 MFMA, product order
// bit-identical to R9 (absmax 0).  XCD swizzle: h -> (h&7)*256 + (h>>3)
__global__ __launch_bounds__(256, 2) void vq_main_kernel(
    const float* __restrict__ z, const u16* __restrict__ EB,
    const float* __restrict__ tnorm, const float* __restrict__ snorm,
    u64* __restrict__ keys) {
  __shared__ __align__(16) u16 zs[4][3][64][40];   // 61440 B, 80B rows (CF)
  __shared__ u64 part[128][2];                      // 2048 B

  const int t   = threadIdx.x;
  const int hb  = blockIdx.x;
  const int bid = (hb & 7) * 256 + (hb >> 3);
  const int pt  = bid >> 3;
  const int ntb = bid & 7;
  const int m0  = pt * 128;
  const int n0  = ntb * 128;
  const int b   = m0 >> 10;
  const int hw0 = m0 & 1023;

  const int l    = t & 63;
  const int wid  = t >> 6;
  const int wpx0 = (wid >> 1) * 64;          // wave pixel base within tile
  const int wcb  = (wid & 1) * 64;           // wave code base within tile
  const int cl   = l & 31;
  const int hi   = l >> 5;
  const int gb   = ntb * 4 + (wid & 1) * 2;  // EB g-base (validated R8 mapping)

  // wave-private staging: lane owns pixel pair (2m_, 2m_+1), k-half h_ (16 k)
  const int m_ = l & 31;
  const int h_ = l >> 5;
  const float* zcol = z + (size_t)b * (EMB_DIM * HW) + hw0 + wpx0 + 2 * m_;

  float2 gz[16];
  bf16x8 geA[3][2], geB[3][2];

  auto load_gz = [&](int kt) {
#pragma unroll
    for (int j = 0; j < 16; ++j)
      gz[j] = *(const float2*)(zcol + (size_t)(kt * 32 + h_ * 16 + j) * HW);
  };
  auto load_ge = [&](bf16x8 dst[3][2], int kt, int ks) {
#pragma unroll
    for (int p = 0; p < 3; ++p)
#pragma unroll
      for (int nn = 0; nn < 2; ++nn)
        dst[p][nn] = *(const bf16x8*)(EB + eb_idx(p, gb + nn, kt, ks, hi, cl));
  };
  auto stage = [&]() {   // split3 + 12 b128 writes into this wave's region
#pragma unroll
    for (int r = 0; r < 2; ++r) {
#pragma unroll
      for (int c = 0; c < 2; ++c) {
        u16x8 vh, vm, vl;
#pragma unroll
        for (int j = 0; j < 8; ++j) {
          const float x = r ? gz[c * 8 + j].y : gz[c * 8 + j].x;
          u16 h3, m3, l3;
          split3(x, h3, m3, l3);
          vh[j] = h3; vm[j] = m3; vl[j] = l3;
        }
        *(u16x8*)&zs[wid][0][2 * m_ + r][h_ * 16 + c * 8] = vh;
        *(u16x8*)&zs[wid][1][2 * m_ + r][h_ * 16 + c * 8] = vm;
        *(u16x8*)&zs[wid][2][2 * m_ + r][h_ * 16 + c * 8] = vl;
      }
    }
  };

  f32x16 acc[2][2];
#pragma unroll
  for (int i = 0; i < 2; ++i)
#pragma unroll
    for (int j = 0; j < 2; ++j)
#pragma unroll
      for (int r = 0; r < 16; ++r) acc[i][j][r] = 0.0f;

  // prologue
  load_gz(0);
  load_ge(geA, 0, 0);
  stage();
  load_gz(1);

  for (int kt = 0; kt < 8; ++kt) {
    load_ge(geB, kt, 1);                       // ks=1 frags (hide under ks=0 MFMA)
    // ks = 0
    {
      bf16x8 af[3][2];
#pragma unroll
      for (int p = 0; p < 3; ++p)
#pragma unroll
        for (int mt = 0; mt < 2; ++mt)
          af[p][mt] = *(const bf16x8*)&zs[wid][p][mt * 32 + cl][hi * 8];
#define PROD(PA, PB, GE)                                                      \
      _Pragma("unroll")                                                       \
      for (int mt = 0; mt < 2; ++mt) {                                        \
        _Pragma("unroll")                                                     \
        for (int nn = 0; nn < 2; ++nn)                                        \
          acc[mt][nn] = __builtin_amdgcn_mfma_f32_32x32x16_bf16(              \
              af[PA][mt], GE[PB][nn], acc[mt][nn], 0, 0, 0);                  \
      }
      PROD(0, 0, geA)
      PROD(0, 1, geA)
      PROD(1, 0, geA)
      PROD(1, 1, geA)
      PROD(0, 2, geA)
      PROD(2, 0, geA)
    }
    if (kt < 7) load_ge(geA, kt + 1, 0);       // next-kt ks=0 frags
    // ks = 1
    {
      bf16x8 af[3][2];
#pragma unroll
      for (int p = 0; p < 3; ++p)
#pragma unroll
        for (int mt = 0; mt < 2; ++mt)
          af[p][mt] = *(const bf16x8*)&zs[wid][p][mt * 32 + cl][16 + hi * 8];
      PROD(0, 0, geB)
      PROD(0, 1, geB)
      PROD(1, 0, geB)
      PROD(1, 1, geB)
      PROD(0, 2, geB)
      PROD(2, 0, geB)
#undef PROD
    }
    if (kt < 7) {
      stage();                                 // overwrite own region (DS in-order)
      if (kt < 6) load_gz(kt + 2);
    }
  }

  // ---- epilogue: d = fl(fl(s+t) - 2m); argmin via u64 keys (order = R9) ----
  const float tv0 = tnorm[n0 + wcb + cl];
  const float tv1 = tnorm[n0 + wcb + 32 + cl];
  u64 bk[2][16];
#pragma unroll
  for (int mt = 0; mt < 2; ++mt)
#pragma unroll
    for (int reg = 0; reg < 16; ++reg) {
      const int row = wpx0 + mt * 32 + (reg & 3) + 8 * (reg >> 2) + 4 * hi;
      const float s = snorm[m0 + row];
      const float d0 = __fsub_rn(__fadd_rn(s, tv0), 2.0f * acc[mt][0][reg]);
      const float d1 = __fsub_rn(__fadd_rn(s, tv1), 2.0f * acc[mt][1][reg]);
      const u64 k0 = ((u64)__float_as_uint(d0) << 32) | (u32)(n0 + wcb + cl);
      const u64 k1 =
          ((u64)__float_as_uint(d1) << 32) | (u32)(n0 + wcb + 32 + cl);
      bk[mt][reg] = k0 < k1 ? k0 : k1;
    }
#pragma unroll
  for (int off = 1; off < 32; off <<= 1) {
#pragma unroll
    for (int mt = 0; mt < 2; ++mt)
#pragma unroll
      for (int reg = 0; reg < 16; ++reg) {
        const u64 o = shfl_xor_u64(bk[mt][reg], off);
        if (o < bk[mt][reg]) bk[mt][reg] = o;
      }
  }

  if (cl == 0) {
#pragma unroll
    for (int mt = 0; mt < 2; ++mt)
#pragma unroll
      for (int reg = 0; reg < 16; ++reg) {
        const int row = wpx0 + mt * 32 + (reg & 3) + 8 * (reg >> 2) + 4 * hi;
        part[row][wid & 1] = bk[mt][reg];
      }
  }
  __syncthreads();                             // the ONLY barrier
  if (t < 128) {
    const u64 a = part[t][0], c = part[t][1];
    atomicMin(&keys[m0 + t], a < c ? a : c);
  }
}

// ---- outputs: z_q gather + straight-through + loss + idx; last block finalizes ----
__global__ __launch_bounds__(256) void vq_outputs_kernel(
    const float* __restrict__ z, const float* __restrict__ emb,
    const u64* __restrict__ keys, float* __restrict__ out,
    float* __restrict__ out_idx_f, double* __restrict__ loss_accum,
    u32* __restrict__ counter, float* __restrict__ out_loss) {
  const int t  = threadIdx.x;
  const int n0 = blockIdx.x * 64;
  const int m  = t & 63;
  const int c0 = t >> 6;
  const int b  = n0 >> 10;
  const int hw = n0 & 1023;
  const float* zb = z   + (size_t)b * (EMB_DIM * HW) + hw + m;
  float*       ob = out + (size_t)b * (EMB_DIM * HW) + hw + m;
  const int idx = (int)(u32)(keys[n0 + m] & 0xffffffffu);
  const float* er = emb + (size_t)idx * EMB_DIM;
  if (c0 == 0) out_idx_f[n0 + m] = (float)idx;

  double lsum = 0.0;
  for (int c = c0; c < EMB_DIM; c += 4) {
    const float e  = er[c];
    const float zv = zb[(size_t)c * HW];
    const float diff = e - zv;       // fl(z_q - z)
    const float zq   = zv + diff;    // straight-through: fl(z + fl(z_q - z))
    ob[(size_t)c * HW] = zq;
    lsum += (double)diff * (double)diff;
  }

  __shared__ double red[256];
  red[t] = lsum;
  __syncthreads();
  for (int s2 = 128; s2 > 0; s2 >>= 1) {
    if (t < s2) red[t] += red[t + s2];
    __syncthreads();
  }
  if (t == 0) {
    atomicAdd(loss_accum, red[0]);
    __threadfence();
    const u32 tick = atomicAdd(counter, 1u);
    if (tick == (u32)(NPIX / 64 - 1)) {
      const double total = atomicAdd(loss_accum, 0.0);  // device-scope read
      const float L = (float)(total / (double)ZQ_ELEMS);
      out_loss[0] = __fadd_rn(L, __fmul_rn(0.25f, L));
    }
  }
}

extern "C" void kernel_launch(void* const* d_in, const int* in_sizes, int n_in,
                              void* d_out, int out_size, void* d_ws, size_t ws_size,
                              hipStream_t stream) {
  const float* z   = (const float*)d_in[0];   // (32, 256, 32, 32) f32
  const float* emb = (const float*)d_in[1];   // (1024, 256) f32

  float* out       = (float*)d_out;           // z_q_out (B,C,H,W)
  float* out_loss  = out + ZQ_ELEMS;          // vq_loss scalar
  float* out_idx_f = out + ZQ_ELEMS + 1;      // encoding_indices as f32

  double* loss_accum = (double*)d_ws;
  float*  tnorm = (float*)((char*)d_ws + WS_TNORM);
  float*  snorm = (float*)((char*)d_ws + WS_SNORM);
  u64*    keys  = (u64*)((char*)d_ws + WS_KEYS);
  u32*    counter = (u32*)((char*)d_ws + WS_CNT);
  u16*    EB    = (u16*)((char*)d_ws + WS_EB);

  vq_prep_kernel<<<132, 256, 0, stream>>>(z, emb, tnorm, snorm, keys, loss_accum,
                                          counter, EB);
  vq_main_kernel<<<2048, 256, 0, stream>>>(z, EB, tnorm, snorm, keys);
  vq_outputs_kernel<<<NPIX / 64, 256, 0, stream>>>(z, emb, keys, out, out_idx_f,
                                                   loss_accum, counter, out_loss);
}